// Round 1
// 458.157 us; speedup vs baseline: 1.0307x; 1.0307x over previous
//
#include <hip/hip_runtime.h>

// ChemResBlock: A=2048 atoms, D=64 depth, F=12 taps.
// out[a,o] = sum_{n,f} conn[a][n*12+f] * Gt[o][n*12+f] + bterm[a,o]
// R7: (1) k_big1 split into pure-streaming k_cvt (fp32->bf16 tiled convert) +
//     k_big for layer 0 (connt is L3-resident right after k_cvt).
//     (2) k_big: 3-buffer pipeline with counted s_waitcnt vmcnt(6) + raw
//     s_barrier (T3+T4) -- no vmcnt(0) drain in the main loop.
//     (3) k_g: W transposed in LDS (ds_read_b128 x3 per d instead of 12x b32),
//     2 atoms per thread.

#define A_N 2048
#define D_N 64
#define F_N 12
#define K_TOTAL (A_N * F_N)        // 24576
#define NSPLIT 32
#define KSEG (K_TOTAL / NSPLIT)    // 768
#define BK 64
#define NKB (KSEG / BK)            // 12

typedef short short8 __attribute__((ext_vector_type(8)));
typedef float f32x16 __attribute__((ext_vector_type(16)));

#define GLOAD16(ldsp, gp)                                                        \
  __builtin_amdgcn_global_load_lds(                                              \
      (const __attribute__((address_space(1))) void*)(gp),                       \
      (__attribute__((address_space(3))) void*)(ldsp), 16, 0, 0)

#define VMWAIT(n) asm volatile("s_waitcnt vmcnt(" #n ")" ::: "memory")

// pack two floats to bf16 pair with round-to-nearest-even
__device__ __forceinline__ unsigned pk_bf16(float a, float b) {
  unsigned ua = __float_as_uint(a);
  unsigned ub = __float_as_uint(b);
  ua += 0x7fffu + ((ua >> 16) & 1u);
  ub += 0x7fffu + ((ub >> 16) & 1u);
  return (ua >> 16) | (ub & 0xffff0000u);
}

__device__ __forceinline__ unsigned short bf16_1(float v) {
  unsigned u = __float_as_uint(v);
  u += 0x7fffu + ((u >> 16) & 1u);
  return (unsigned short)(u >> 16);
}

// ---------------- prep: x transpose (blocks 0..31) + bterm (blocks 32..543) ----------------
__global__ void k_prep(const float* __restrict__ x, float* __restrict__ xt,
                       const float* __restrict__ bond, const float* __restrict__ f0,
                       const float* __restrict__ f1, float* __restrict__ bt0,
                       float* __restrict__ bt1) {
  int t = threadIdx.x;
  if (blockIdx.x < 32) {
    __shared__ float ld[64][65];
    int m0 = blockIdx.x * 64;
    int r = t >> 2, cq = (t & 3) * 16;
    const float4* src = (const float4*)(x + (size_t)(m0 + r) * 64 + cq);
#pragma unroll
    for (int i = 0; i < 4; ++i) {
      float4 v = src[i];
      ld[r][cq + i * 4 + 0] = v.x;
      ld[r][cq + i * 4 + 1] = v.y;
      ld[r][cq + i * 4 + 2] = v.z;
      ld[r][cq + i * 4 + 3] = v.w;
    }
    __syncthreads();
    int c = t >> 2, ml0 = (t & 3) * 16;
    float4* dst = (float4*)(xt + (size_t)c * 2048 + m0 + ml0);
#pragma unroll
    for (int i = 0; i < 4; ++i) {
      float4 v;
      v.x = ld[ml0 + i * 4 + 0][c];
      v.y = ld[ml0 + i * 4 + 1][c];
      v.z = ld[ml0 + i * 4 + 2][c];
      v.w = ld[ml0 + i * 4 + 3][c];
      dst[i] = v;
    }
  } else {
    int b = blockIdx.x - 32;           // 0..511
    int a = (b & 31) * 64 + (t & 63);
    int o = (b >> 5) * 4 + (t >> 6);
    float s0 = 0.f, s1 = 0.f;
#pragma unroll
    for (int f = 0; f < F_N; ++f) {
#pragma unroll
      for (int j = 0; j < 2; ++j) {
        float bv = bond[a * 24 + f * 2 + j];
        s0 += bv * f0[o * 792 + f * 66 + 64 + j];
        s1 += bv * f1[o * 792 + f * 66 + 64 + j];
      }
    }
    bt0[o * 2048 + a] = s0;
    bt1[o * 2048 + a] = s1;
  }
}

// ---------------- one-shot: conn fp32 -> tiled bf16 connt (pure streaming) ----------------
// grid (NKB, NSPLIT, 16); block handles one [128 rows][64 k] tile.
// tile[row*64 + c] = bf16(conn[atile*128+row][ks*768 + kb*64 + c])
__global__ void k_cvt(const float* __restrict__ conn, unsigned short* __restrict__ connt) {
  int t = threadIdx.x;
  int kb = blockIdx.x, ks = blockIdx.y, atile = blockIdx.z;
  const float* src = conn + (size_t)(atile * 128) * K_TOTAL + ks * KSEG + kb * 64;
  unsigned short* dst = connt + (size_t)((atile * NSPLIT + ks) * NKB + kb) * 8192;
  int r0 = t >> 3, c0 = (t & 7) * 8;
#pragma unroll
  for (int i = 0; i < 4; ++i) {
    int row = r0 + i * 32;
    const float4* s4 = (const float4*)(src + (size_t)row * K_TOTAL + c0);
    float4 a = s4[0], b = s4[1];
    uint4 p;
    p.x = pk_bf16(a.x, a.y);
    p.y = pk_bf16(a.z, a.w);
    p.z = pk_bf16(b.x, b.y);
    p.w = pk_bf16(b.z, b.w);
    *(uint4*)(dst + row * 64 + c0) = p;
  }
}

// ---------------- per-layer: Gt -> tiled gtt[q][o][c], q = k>>6 ----------------
// WT[d][f] transposed in LDS: 3x ds_read_b128 per d (broadcast), 2 atoms/thread.
__global__ void k_g(const float* __restrict__ vt, const float* __restrict__ filt,
                    unsigned short* __restrict__ gtt) {
  __shared__ __align__(16) float WT[64][12];   // row = 48 B, float4-aligned
  int o = blockIdx.y;
  int t = threadIdx.x;
  for (int i = t; i < 768; i += 256) {
    int d = i / 12, f = i % 12;
    WT[d][f] = filt[o * 792 + f * 66 + d];
  }
  __syncthreads();
  int n0 = blockIdx.x * 512 + t;               // second atom at n0+256
  float acc0[12], acc1[12];
#pragma unroll
  for (int f = 0; f < 12; ++f) { acc0[f] = 0.f; acc1[f] = 0.f; }
#pragma unroll 4
  for (int d = 0; d < 64; ++d) {
    float v0 = vt[d * 2048 + n0];
    float v1 = vt[d * 2048 + n0 + 256];
    const float4* wp = (const float4*)WT[d];
    float4 w0 = wp[0], w1 = wp[1], w2 = wp[2];
    acc0[0] += v0 * w0.x;  acc0[1] += v0 * w0.y;  acc0[2]  += v0 * w0.z;  acc0[3]  += v0 * w0.w;
    acc0[4] += v0 * w1.x;  acc0[5] += v0 * w1.y;  acc0[6]  += v0 * w1.z;  acc0[7]  += v0 * w1.w;
    acc0[8] += v0 * w2.x;  acc0[9] += v0 * w2.y;  acc0[10] += v0 * w2.z;  acc0[11] += v0 * w2.w;
    acc1[0] += v1 * w0.x;  acc1[1] += v1 * w0.y;  acc1[2]  += v1 * w0.z;  acc1[3]  += v1 * w0.w;
    acc1[4] += v1 * w1.x;  acc1[5] += v1 * w1.y;  acc1[6]  += v1 * w1.z;  acc1[7]  += v1 * w1.w;
    acc1[8] += v1 * w2.x;  acc1[9] += v1 * w2.y;  acc1[10] += v1 * w2.z;  acc1[11] += v1 * w2.w;
  }
  int kb0 = n0 * 12;
#pragma unroll
  for (int f = 0; f < F_N; ++f) {
    int k = kb0 + f;
    gtt[(size_t)(k >> 6) * 4096 + o * 64 + (k & 63)] = bf16_1(acc0[f]);
  }
  int kb1 = (n0 + 256) * 12;
#pragma unroll
  for (int f = 0; f < F_N; ++f) {
    int k = kb1 + f;
    gtt[(size_t)(k >> 6) * 4096 + o * 64 + (k & 63)] = bf16_1(acc1[f]);
  }
}

// ---------------- all 4 layers: split-K GEMM, 3-buffer counted-vmcnt pipeline ----------------
__launch_bounds__(256, 2)
__global__ void k_big(const unsigned short* __restrict__ connt,
                      const unsigned short* __restrict__ gtt, float* __restrict__ part) {
  __shared__ __align__(16) unsigned short smem[36864];  // 3 x (16KB conn + 8KB gt) = 72 KB
  int t = threadIdx.x, lane = t & 63, w = t >> 6;
  int atile = blockIdx.x, ks = blockIdx.y;
  const unsigned short* ct = connt + (size_t)(atile * NSPLIT + ks) * (NKB * 8192);
  const unsigned short* gs = gtt + (size_t)ks * (NKB * 4096);

  int rl = lane >> 3, sl = lane & 7;
  int cs = sl ^ rl;

  int cSrc[4], gSrc[2], cDst[4], gDst[2];
#pragma unroll
  for (int j = 0; j < 4; ++j) {
    cSrc[j] = (w * 32 + j * 8 + rl) * 64 + cs * 8;
    cDst[j] = (w * 32 + j * 8) * 64;          // wave-uniform LDS base (glds appends lane*16B)
  }
#pragma unroll
  for (int j = 0; j < 2; ++j) {
    gSrc[j] = (w * 16 + j * 8 + rl) * 64 + cs * 8;
    gDst[j] = 8192 + (w * 16 + j * 8) * 64;
  }

  f32x16 acc0, acc1;
#pragma unroll
  for (int i = 0; i < 16; ++i) { acc0[i] = 0.f; acc1[i] = 0.f; }

  int oh = w >> 1, ah = w & 1;
  int orow = oh * 32 + (lane & 31);
  int arow = ah * 64 + (lane & 31);
  int sw = lane & 7;
  int khalf = lane >> 5;

  // prologue: prefetch tiles 0,1 (12 vm-ops/wave outstanding)
#pragma unroll
  for (int p = 0; p < 2; ++p) {
    unsigned short* base = smem + p * 12288;
#pragma unroll
    for (int j = 0; j < 4; ++j) GLOAD16(base + cDst[j], ct + p * 8192 + cSrc[j]);
#pragma unroll
    for (int j = 0; j < 2; ++j) GLOAD16(base + gDst[j], gs + p * 4096 + gSrc[j]);
  }

#pragma unroll
  for (int kb = 0; kb < NKB; ++kb) {
    // outstanding here: tiles kb (6) + kb+1 (6). vmcnt(6) => tile kb landed.
    if (kb < NKB - 1) VMWAIT(6);
    else VMWAIT(0);
    __builtin_amdgcn_s_barrier();          // collective visibility of tile kb
    asm volatile("" ::: "memory");         // keep LDS reads below the barrier
    if (kb + 2 < NKB) {                    // issue tile kb+2 into buf (kb-1)%3 (reads done)
      unsigned short* base = smem + ((kb + 2) % 3) * 12288;
#pragma unroll
      for (int j = 0; j < 4; ++j) GLOAD16(base + cDst[j], ct + (kb + 2) * 8192 + cSrc[j]);
#pragma unroll
      for (int j = 0; j < 2; ++j) GLOAD16(base + gDst[j], gs + (kb + 2) * 4096 + gSrc[j]);
    }
    const unsigned short* cb = smem + (kb % 3) * 12288;
    const unsigned short* gb = cb + 8192;
#pragma unroll
    for (int kk = 0; kk < 4; ++kk) {
      int c = kk * 2 + khalf;
      int coff = ((c ^ sw) << 3);
      short8 af = *(const short8*)(gb + orow * 64 + coff);
      short8 b0 = *(const short8*)(cb + arow * 64 + coff);
      short8 b1 = *(const short8*)(cb + (arow + 32) * 64 + coff);
      acc0 = __builtin_amdgcn_mfma_f32_32x32x16_bf16(af, b0, acc0, 0, 0, 0);
      acc1 = __builtin_amdgcn_mfma_f32_32x32x16_bf16(af, b1, acc1, 0, 0, 0);
    }
  }

  float* pp = part + (size_t)ks * (64 * 2048);
  int a0 = atile * 128 + ah * 64 + (lane & 31);
  int ob = oh * 32 + 4 * khalf;
#pragma unroll
  for (int rg = 0; rg < 16; ++rg) {
    int o = ob + (rg & 3) + 8 * (rg >> 2);
    pp[o * 2048 + a0] = acc0[rg];
    pp[o * 2048 + a0 + 32] = acc1[rg];
  }
}

// ---------------- per-layer epilogue: sum partials + bterm (+x) + relu (float4) ----------------
__global__ void k_reduce(const float* __restrict__ part, const float* __restrict__ bt,
                         const float* __restrict__ xt, float* __restrict__ curt,
                         float* __restrict__ outp, int residual, int final_layer) {
  int i4 = blockIdx.x * 256 + threadIdx.x;  // float4 index, 0..32767; layout [o][m]
  float4 s = ((const float4*)bt)[i4];
#pragma unroll
  for (int sI = 0; sI < NSPLIT; ++sI) {
    float4 p = ((const float4*)part)[(size_t)sI * 32768 + i4];
    s.x += p.x; s.y += p.y; s.z += p.z; s.w += p.w;
  }
  if (residual) {
    float4 r = ((const float4*)xt)[i4];
    s.x += r.x; s.y += r.y; s.z += r.z; s.w += r.w;
  }
  s.x = fmaxf(s.x, 0.f); s.y = fmaxf(s.y, 0.f);
  s.z = fmaxf(s.z, 0.f); s.w = fmaxf(s.w, 0.f);
  ((float4*)curt)[i4] = s;
  if (final_layer) {
    int idx = i4 * 4;
    int o = idx >> 11, m = idx & 2047;
    outp[(m + 0) * 64 + o] = s.x;
    outp[(m + 1) * 64 + o] = s.y;
    outp[(m + 2) * 64 + o] = s.z;
    outp[(m + 3) * 64 + o] = s.w;
  }
}

extern "C" void kernel_launch(void* const* d_in, const int* in_sizes, int n_in,
                              void* d_out, int out_size, void* d_ws, size_t ws_size,
                              hipStream_t stream) {
  const float* x    = (const float*)d_in[0];  // (2048, 64)
  const float* conn = (const float*)d_in[1];  // (2048, 2048, 12)
  const float* bond = (const float*)d_in[2];  // (2048, 12, 2)
  const float* f0   = (const float*)d_in[3];  // (64, 12, 66)
  const float* f1   = (const float*)d_in[4];
  float* out = (float*)d_out;                 // (2048, 64)

  char* ws = (char*)d_ws;
  float* xt   = (float*)(ws + 0);              // 64x2048 fp32            512 KB
  float* curt = (float*)(ws + 524288);         // 64x2048 fp32            512 KB
  float* bt0  = (float*)(ws + 1048576);        // 64x2048 fp32            512 KB
  float* bt1  = (float*)(ws + 1572864);        // 64x2048 fp32            512 KB
  unsigned short* gtt = (unsigned short*)(ws + 2097152);     // tiled gt    3 MB
  float* part = (float*)(ws + 5242880);        // 32 x 64x2048 fp32       16 MB
  unsigned short* connt = (unsigned short*)(ws + 33554432);  // tiled conn  96 MB
  // total ~128 MB of d_ws used

  k_prep<<<544, 256, 0, stream>>>(x, xt, bond, f0, f1, bt0, bt1);
  k_cvt<<<dim3(NKB, NSPLIT, 16), 256, 0, stream>>>(conn, connt);

  for (int layer = 0; layer < 4; ++layer) {
    const float* filt = (layer < 2) ? f0 : f1;
    const float* bt   = (layer < 2) ? bt0 : bt1;
    const float* vin  = (layer == 0) ? xt : curt;
    k_g<<<dim3(4, 64), 256, 0, stream>>>(vin, filt, gtt);
    k_big<<<dim3(16, NSPLIT), 256, 0, stream>>>(connt, gtt, part);
    k_reduce<<<128, 256, 0, stream>>>(part, bt, xt, curt, out, layer & 1, layer == 3);
  }
}